// Round 1
// baseline (172.996 us; speedup 1.0000x reference)
//
#include <hip/hip_runtime.h>
#include <math.h>

#define NPATCH 24
#define NB 4
#define MPTS 256
#define MT 4096
#define NPTS (NPATCH*MPTS)   // 6144
#define GRIDPTS 64
#define SIGMA2INV 100.0f     // 1/sigma^2, sigma=0.1

// ---------- helpers ----------

__device__ inline unsigned encodeFloat(float f) {
    unsigned u = __float_as_uint(f);
    return (u & 0x80000000u) ? ~u : (u | 0x80000000u);
}
__device__ inline float decodeFloat(unsigned e) {
    return __uint_as_float((e & 0x80000000u) ? (e ^ 0x80000000u) : ~e);
}

template<int NV>
__device__ inline void blockReduceSumN(const float* vals, float* out, float* scratch) {
    // 256 threads = 4 waves. out[NV] in LDS valid for all threads after return.
    int wid = threadIdx.x >> 6, lane = threadIdx.x & 63;
#pragma unroll
    for (int i = 0; i < NV; ++i) {
        float v = vals[i];
        for (int o = 32; o > 0; o >>= 1) v += __shfl_down(v, o);
        if (lane == 0) scratch[wid * NV + i] = v;
    }
    __syncthreads();
    if (threadIdx.x < NV)
        out[threadIdx.x] = scratch[0 * NV + threadIdx.x] + scratch[1 * NV + threadIdx.x] +
                           scratch[2 * NV + threadIdx.x] + scratch[3 * NV + threadIdx.x];
    __syncthreads();
}

// exact port of _pt_tri_sqdist (where-chain order preserved: later overrides earlier)
__device__ inline float ptTriSqDist(float px, float py, float pz,
                                    float ax, float ay, float az,
                                    float bx, float by, float bz,
                                    float cx, float cy, float cz) {
    float abx = bx - ax, aby = by - ay, abz = bz - az;
    float acx = cx - ax, acy = cy - ay, acz = cz - az;
    float apx = px - ax, apy = py - ay, apz = pz - az;
    float d1 = abx * apx + aby * apy + abz * apz;
    float d2 = acx * apx + acy * apy + acz * apz;
    float bpx = px - bx, bpy = py - by, bpz = pz - bz;
    float d3 = abx * bpx + aby * bpy + abz * bpz;
    float d4 = acx * bpx + acy * bpy + acz * bpz;
    float cpx = px - cx, cpy = py - cy, cpz = pz - cz;
    float d5 = abx * cpx + aby * cpy + abz * cpz;
    float d6 = acx * cpx + acy * cpy + acz * cpz;
    float vc = d1 * d4 - d3 * d2;
    float vb = d5 * d2 - d1 * d6;
    float va = d3 * d6 - d5 * d4;
    auto safe = [](float x) { return fabsf(x) < 1e-12f ? 1e-12f : x; };
    auto clamp01 = [](float x) { return fminf(fmaxf(x, 0.0f), 1.0f); };
    float t_ab = clamp01(d1 / safe(d1 - d3));
    float t_ac = clamp01(d2 / safe(d2 - d6));
    float t_bc = clamp01((d4 - d3) / safe((d4 - d3) + (d5 - d6)));
    float denom = safe(va + vb + vc);
    float v = vb / denom, w = vc / denom;
    float clx = ax + abx * v + acx * w;
    float cly = ay + aby * v + acy * w;
    float clz = az + abz * v + acz * w;
    if (va <= 0.0f && (d4 - d3) >= 0.0f && (d5 - d6) >= 0.0f) {
        clx = bx + (cx - bx) * t_bc; cly = by + (cy - by) * t_bc; clz = bz + (cz - bz) * t_bc;
    }
    if (vb <= 0.0f && d2 >= 0.0f && d6 <= 0.0f) {
        clx = ax + acx * t_ac; cly = ay + acy * t_ac; clz = az + acz * t_ac;
    }
    if (d6 >= 0.0f && d5 <= d6) { clx = cx; cly = cy; clz = cz; }
    if (vc <= 0.0f && d1 >= 0.0f && d3 <= 0.0f) {
        clx = ax + abx * t_ab; cly = ay + aby * t_ab; clz = az + abz * t_ab;
    }
    if (d3 >= 0.0f && d4 <= d3) { clx = bx; cly = by; clz = bz; }
    if (d1 <= 0.0f && d2 <= 0.0f) { clx = ax; cly = ay; clz = az; }
    float dx = px - clx, dy = py - cly, dz = pz - clz;
    return dx * dx + dy * dy + dz * dz;
}

// ---------- kernel 1: Coons sampling + bboxes ----------
__global__ __launch_bounds__(64) void k_coons(const float* __restrict__ patches,
                                              float* __restrict__ grid,
                                              float* __restrict__ bbF,
                                              float* __restrict__ bbE) {
    int bp = blockIdx.x;            // b*24 + p
    int m = threadIdx.x;            // 0..63
    int i = m >> 3, j = m & 7;
    float s = (i == 7) ? 1.0f : (float)i * (1.0f / 7.0f);
    float t = (j == 7) ? 1.0f : (float)j * (1.0f / 7.0f);
    const float* cp = patches + bp * 36;
    float bs[4], bt[4], bs1[4], bt1[4];
    {
        float u, vv;
        u = s; vv = 1.0f - u; bs[0] = vv * vv * vv; bs[1] = 3.f * u * vv * vv; bs[2] = 3.f * u * u * vv; bs[3] = u * u * u;
        u = t; vv = 1.0f - u; bt[0] = vv * vv * vv; bt[1] = 3.f * u * vv * vv; bt[2] = 3.f * u * u * vv; bt[3] = u * u * u;
        u = 1.0f - s; vv = 1.0f - u; bs1[0] = vv * vv * vv; bs1[1] = 3.f * u * vv * vv; bs1[2] = 3.f * u * u * vv; bs1[3] = u * u * u;
        u = 1.0f - t; vv = 1.0f - u; bt1[0] = vv * vv * vv; bt1[1] = 3.f * u * vv * vv; bt1[2] = 3.f * u * u * vv; bt1[3] = u * u * u;
    }
    float g[3];
#pragma unroll
    for (int c = 0; c < 3; ++c) {
        float cb = bs[0] * cp[0 * 3 + c] + bs[1] * cp[1 * 3 + c] + bs[2] * cp[2 * 3 + c] + bs[3] * cp[3 * 3 + c];
        float cr = bt[0] * cp[3 * 3 + c] + bt[1] * cp[4 * 3 + c] + bt[2] * cp[5 * 3 + c] + bt[3] * cp[6 * 3 + c];
        float ct = bs1[0] * cp[6 * 3 + c] + bs1[1] * cp[7 * 3 + c] + bs1[2] * cp[8 * 3 + c] + bs1[3] * cp[9 * 3 + c];
        float cl = bt1[0] * cp[9 * 3 + c] + bt1[1] * cp[10 * 3 + c] + bt1[2] * cp[11 * 3 + c] + bt1[3] * cp[0 * 3 + c];
        float P00 = cp[0 * 3 + c], P10 = cp[3 * 3 + c], P11 = cp[6 * 3 + c], P01 = cp[9 * 3 + c];
        float ruled = (1.0f - t) * cb + t * ct + (1.0f - s) * cl + s * cr;
        float bil = (1.0f - s) * (1.0f - t) * P00 + s * (1.0f - t) * P10 + s * t * P11 + (1.0f - s) * t * P01;
        g[c] = ruled - bil;
        grid[(bp * GRIDPTS + m) * 3 + c] = g[c];
    }
    // wave-reduce bboxes (full patch + edge row m>=56)
    float mnF[3], mxF[3], mnE[3], mxE[3];
    bool edge = (m >= 56);
#pragma unroll
    for (int c = 0; c < 3; ++c) {
        mnF[c] = g[c]; mxF[c] = g[c];
        mnE[c] = edge ? g[c] : 1e30f;
        mxE[c] = edge ? g[c] : -1e30f;
    }
    for (int o = 32; o > 0; o >>= 1) {
#pragma unroll
        for (int c = 0; c < 3; ++c) {
            mnF[c] = fminf(mnF[c], __shfl_down(mnF[c], o));
            mxF[c] = fmaxf(mxF[c], __shfl_down(mxF[c], o));
            mnE[c] = fminf(mnE[c], __shfl_down(mnE[c], o));
            mxE[c] = fmaxf(mxE[c], __shfl_down(mxE[c], o));
        }
    }
    if (m == 0) {
#pragma unroll
        for (int c = 0; c < 3; ++c) {
            bbF[bp * 6 + c] = mnF[c]; bbF[bp * 6 + 3 + c] = mxF[c];
            bbE[bp * 6 + c] = mnE[c]; bbE[bp * 6 + 3 + c] = mxE[c];
        }
    }
}

// ---------- kernel 2: chamfer A (each point -> nearest target), chunked over targets ----------
__global__ __launch_bounds__(256) void k_chamfer_a(const float* __restrict__ target,
                                                   const float* __restrict__ points,
                                                   unsigned long long* __restrict__ best_a) {
    int tc = blockIdx.x;   // 0..7 target chunk (512 each)
    int p = blockIdx.y;    // 0..23
    int b = blockIdx.z;    // 0..3
    int tid = threadIdx.x;
    __shared__ float4 tg[512];
    for (int k = tid; k < 512; k += 256) {
        const float* tp = target + (size_t)(b * MT + tc * 512 + k) * 6;
        float x = tp[0], y = tp[1], z = tp[2];
        tg[k] = make_float4(x, y, z, x * x + y * y + z * z);
    }
    __syncthreads();
    const float* pp = points + (size_t)((b * NPATCH + p) * MPTS + tid) * 3;
    float px = pp[0], py = pp[1], pz = pp[2];
    float pn = px * px + py * py + pz * pz;
    float bestd = 1e30f;
    int besti = 0;
#pragma unroll 4
    for (int k = 0; k < 512; ++k) {
        float4 T = tg[k];
        float dot = px * T.x + py * T.y + pz * T.z;
        float d = (pn + T.w) - 2.0f * dot;
        if (d < bestd) { bestd = d; besti = k; }
    }
    unsigned long long key = ((unsigned long long)encodeFloat(bestd) << 32) |
                             (unsigned)(tc * 512 + besti);
    atomicMin(&best_a[(size_t)b * NPTS + p * MPTS + tid], key);
}

// ---------- kernel 3: chamfer B (each target -> nearest point), chunked over points ----------
__global__ __launch_bounds__(256) void k_chamfer_b(const float* __restrict__ points,
                                                   const float* __restrict__ target,
                                                   unsigned long long* __restrict__ best_b) {
    int nc = blockIdx.x;   // 0..11 point chunk (512 each)
    int mc = blockIdx.y;   // 0..15 target block (256 each)
    int b = blockIdx.z;
    int tid = threadIdx.x;
    __shared__ float4 pt[512];
    for (int k = tid; k < 512; k += 256) {
        const float* pp = points + (size_t)(b * NPTS + nc * 512 + k) * 3;
        float x = pp[0], y = pp[1], z = pp[2];
        pt[k] = make_float4(x, y, z, x * x + y * y + z * z);
    }
    __syncthreads();
    int mt = mc * 256 + tid;
    const float* tp = target + (size_t)(b * MT + mt) * 6;
    float tx = tp[0], ty = tp[1], tz = tp[2];
    float tn2 = tx * tx + ty * ty + tz * tz;
    float bestd = 1e30f;
    int besti = 0;
#pragma unroll 4
    for (int k = 0; k < 512; ++k) {
        float4 P = pt[k];
        float dot = tx * P.x + ty * P.y + tz * P.z;
        float d = (tn2 + P.w) - 2.0f * dot;
        if (d < bestd) { bestd = d; besti = k; }
    }
    unsigned long long key = ((unsigned long long)encodeFloat(bestd) << 32) |
                             (unsigned)(nc * 512 + besti);
    atomicMin(&best_b[(size_t)b * MT + mt], key);
}

// ---------- kernel 4: finalize A + template-normals + planar (per (b,p) block) ----------
// acc layout: [0..3] sum(mtd*ca) per b, [4..7] sum(mtd*na), [8..11] sum(mtd),
//             [12..15] sum cb per b, [16..19] sum nb, [20] tpl ratios, [21] planar ratios, [22] collision
__global__ __launch_bounds__(256) void k_final_a(const float* __restrict__ points,
                                                 const float* __restrict__ normals,
                                                 const float* __restrict__ target,
                                                 const float* __restrict__ mtds,
                                                 const float* __restrict__ st,
                                                 const float* __restrict__ tmpl,
                                                 const unsigned long long* __restrict__ best_a,
                                                 float* __restrict__ acc) {
    int p = blockIdx.x, b = blockIdx.y;
    int m = threadIdx.x;
    int bp = b * NPATCH + p;
    const float* pp = points + (size_t)(bp * MPTS + m) * 3;
    float px = pp[0], py = pp[1], pz = pp[2];
    const float* nr = normals + (size_t)(bp * MPTS + m) * 3;
    float nx = nr[0], ny = nr[1], nz = nr[2];
    float w = mtds[bp * MPTS + m];
    float s = st[2 * m], t = st[2 * m + 1];
    unsigned long long pk = best_a[(size_t)b * NPTS + p * MPTS + m];
    float ca = decodeFloat((unsigned)(pk >> 32));
    int ia = (int)(pk & 0xffffffffu);
    const float* tq = target + (size_t)(b * MT + ia) * 6 + 3;
    float dx = nx - tq[0], dy = ny - tq[1], dz = nz - tq[2];
    float na = dx * dx + dy * dy + dz * dz;
    const float* tm = tmpl + (size_t)(p * MPTS + m) * 3;
    float ex = tm[0] - nx, ey = tm[1] - ny, ez = tm[2] - nz;
    float tnl = ex * ex + ey * ey + ez * ez;

    float vals[18];
    vals[0] = w * ca; vals[1] = w * na; vals[2] = w; vals[3] = w * tnl;
    vals[4] = s * px; vals[5] = s * py; vals[6] = s * pz;     // Atp row k=0 (s)
    vals[7] = t * px; vals[8] = t * py; vals[9] = t * pz;     // k=1 (t)
    vals[10] = px; vals[11] = py; vals[12] = pz;              // k=2 (1)
    vals[13] = s * s; vals[14] = s * t; vals[15] = s; vals[16] = t * t; vals[17] = t;

    __shared__ float scratch[4 * 18];
    __shared__ float red[18];
    blockReduceSumN<18>(vals, red, scratch);

    __shared__ float sol[9];
    __shared__ float smtd_sh;
    if (threadIdx.x == 0) {
        float a00 = red[13], a01 = red[14], a02 = red[15];
        float a11 = red[16], a12 = red[17], a22 = 256.0f;
        float c00 = a11 * a22 - a12 * a12;
        float c01 = a02 * a12 - a01 * a22;
        float c02 = a01 * a12 - a02 * a11;
        float det = a00 * c00 + a01 * c01 + a02 * c02;
        float id = 1.0f / det;
        float i00 = c00 * id, i01 = c01 * id, i02 = c02 * id;
        float i11 = (a00 * a22 - a02 * a02) * id;
        float i12 = (a01 * a02 - a00 * a12) * id;
        float i22 = (a00 * a11 - a01 * a01) * id;
#pragma unroll
        for (int c = 0; c < 3; ++c) {
            float b0 = red[4 + c], b1 = red[7 + c], b2 = red[10 + c];
            sol[0 * 3 + c] = i00 * b0 + i01 * b1 + i02 * b2;
            sol[1 * 3 + c] = i01 * b0 + i11 * b1 + i12 * b2;
            sol[2 * 3 + c] = i02 * b0 + i12 * b1 + i22 * b2;
        }
        smtd_sh = red[2];
        atomicAdd(&acc[0 + b], red[0]);
        atomicAdd(&acc[4 + b], red[1]);
        atomicAdd(&acc[8 + b], red[2]);
        atomicAdd(&acc[20], red[3] / red[2]);   // per-(b,p) template ratio
    }
    __syncthreads();
    float rx = px - (s * sol[0] + t * sol[3] + sol[6]);
    float ry = py - (s * sol[1] + t * sol[4] + sol[7]);
    float rz = pz - (s * sol[2] + t * sol[5] + sol[8]);
    float v2 = w * (rx * rx + ry * ry + rz * rz);
    for (int o = 32; o > 0; o >>= 1) v2 += __shfl_down(v2, o);
    __shared__ float s2[4];
    if ((threadIdx.x & 63) == 0) s2[threadIdx.x >> 6] = v2;
    __syncthreads();
    if (threadIdx.x == 0)
        atomicAdd(&acc[21], (s2[0] + s2[1] + s2[2] + s2[3]) / smtd_sh);
}

// ---------- kernel 5: finalize B ----------
__global__ __launch_bounds__(256) void k_final_b(const float* __restrict__ target,
                                                 const float* __restrict__ normals,
                                                 const unsigned long long* __restrict__ best_b,
                                                 float* __restrict__ acc) {
    int mc = blockIdx.x, b = blockIdx.y;
    int mt = mc * 256 + threadIdx.x;
    unsigned long long pk = best_b[(size_t)b * MT + mt];
    float cb = decodeFloat((unsigned)(pk >> 32));
    int ib = (int)(pk & 0xffffffffu);
    const float* tq = target + (size_t)(b * MT + mt) * 6 + 3;
    const float* nr = normals + (size_t)(b * NPTS + ib) * 3;
    float dx = tq[0] - nr[0], dy = tq[1] - nr[1], dz = tq[2] - nr[2];
    float nb = dx * dx + dy * dy + dz * dz;
    float vals[2] = {cb, nb};
    __shared__ float scratch[4 * 2];
    __shared__ float red[2];
    blockReduceSumN<2>(vals, red, scratch);
    if (threadIdx.x == 0) {
        atomicAdd(&acc[12 + b], red[0]);
        atomicAdd(&acc[16 + b], red[1]);
    }
}

// ---------- kernel 6: collision ----------
__global__ __launch_bounds__(256) void k_collision(const float* __restrict__ grid,
                                                   const float* __restrict__ bbF,
                                                   const float* __restrict__ bbE,
                                                   float* __restrict__ acc) {
    int pair = blockIdx.x;   // 0..275 (24 adjacent + 252 non-adjacent)
    int b = blockIdx.y;
    bool adj = pair < 24;
    int i1, i2;
    if (adj) {
        i1 = pair; i2 = (pair + 1) % NPATCH;
    } else {
        int k = pair - 24;
        i1 = 0;
        while (i1 < NPATCH) {
            int cnt = (i1 == 0) ? 21 : (22 - i1);
            if (k < cnt) break;
            k -= cnt; ++i1;
        }
        i2 = i1 + 2 + k;
    }
    // mask = any over batch of bbox intersect
    bool mask = false;
    for (int bb = 0; bb < NB; ++bb) {
        const float* B1 = (adj ? bbE : bbF) + (bb * NPATCH + i1) * 6;
        const float* B2 = bbF + (bb * NPATCH + i2) * 6;
        bool it = (B1[3] >= B2[0]) && (B2[3] >= B1[0]) &&
                  (B1[4] >= B2[1]) && (B2[4] >= B1[1]) &&
                  (B1[5] >= B2[2]) && (B2[5] >= B1[2]);
        mask |= it;
    }
    if (!mask) return;
    __shared__ float P1[192], P2[192];
    int tid = threadIdx.x;
    for (int k = tid; k < 192; k += 256) {
        P1[k] = grid[(size_t)(b * NPATCH + i1) * 192 + k];
        P2[k] = grid[(size_t)(b * NPATCH + i2) * 192 + k];
    }
    __syncthreads();
    float best = 1e30f;
    int ntests = adj ? (8 * 98 + 64 * 7) : (2 * 64 * 98);
    for (int tt = tid; tt < ntests; tt += 256) {
        int pi, va, vb, vc;
        const float *PS, *TS;
        if (adj) {
            if (tt < 784) {
                int ptI = tt / 98, tri = tt % 98;
                pi = 56 + ptI; PS = P1; TS = P2;
                int cell = tri >> 1, ii = cell / 7, jj = cell % 7;
                int v00 = ii * 8 + jj;
                if (tri & 1) { va = v00 + 8; vb = v00 + 9; vc = v00 + 1; }
                else         { va = v00;     vb = v00 + 8; vc = v00 + 1; }
            } else {
                int r = tt - 784;
                int ptI = r / 7, tri = r % 7;
                pi = ptI; PS = P2; TS = P1;
                va = 56 + tri; vb = 57 + tri; vc = 49 + tri;  // [v10,v11,v01] of cell (6,tri)
            }
        } else {
            int dir = tt / 6272, r = tt % 6272;
            int ptI = r / 98, tri = r % 98;
            int cell = tri >> 1, ii = cell / 7, jj = cell % 7;
            int v00 = ii * 8 + jj;
            if (tri & 1) { va = v00 + 8; vb = v00 + 9; vc = v00 + 1; }
            else         { va = v00;     vb = v00 + 8; vc = v00 + 1; }
            if (dir == 0) { pi = ptI; PS = P1; TS = P2; }
            else          { pi = ptI; PS = P2; TS = P1; }
        }
        float d2 = ptTriSqDist(PS[pi * 3], PS[pi * 3 + 1], PS[pi * 3 + 2],
                               TS[va * 3], TS[va * 3 + 1], TS[va * 3 + 2],
                               TS[vb * 3], TS[vb * 3 + 1], TS[vb * 3 + 2],
                               TS[vc * 3], TS[vc * 3 + 1], TS[vc * 3 + 2]);
        best = fminf(best, d2);
    }
    for (int o = 32; o > 0; o >>= 1) best = fminf(best, __shfl_down(best, o));
    __shared__ float sm[4];
    if ((tid & 63) == 0) sm[tid >> 6] = best;
    __syncthreads();
    if (tid == 0) {
        float d2 = fminf(fminf(sm[0], sm[1]), fminf(sm[2], sm[3]));
        atomicAdd(&acc[22], expf(-(d2 + 1e-12f) * SIGMA2INV));
    }
}

// ---------- kernel 7: combine ----------
__global__ void k_finish(const float* __restrict__ acc, float* __restrict__ out) {
    if (threadIdx.x == 0 && blockIdx.x == 0) {
        float ch = 0.0f, no = 0.0f;
        for (int b = 0; b < NB; ++b) {
            float caw = acc[0 + b] / acc[8 + b];
            float naw = acc[4 + b] / acc[8 + b];
            float cbm = acc[12 + b] / (float)MT;
            float nbm = acc[16 + b] / (float)MT;
            ch += caw + cbm;
            no += naw + nbm;
        }
        ch = ch * 0.25f * 0.5f;
        no = no * 0.25f * 0.5f;
        float tpl = acc[20] / 96.0f;
        float pl = acc[21] / 96.0f;
        float col = acc[22] * 0.25f;
        float loss = ch + no + 0.01f * col + pl + tpl;
        out[0] = loss;
        out[1] = ch;
        out[2] = no;
        out[3] = col;
        out[4] = pl;
        out[5] = tpl;
        out[6] = 0.0f;
    }
}

// ---------- launch ----------
extern "C" void kernel_launch(void* const* d_in, const int* in_sizes, int n_in,
                              void* d_out, int out_size, void* d_ws, size_t ws_size,
                              hipStream_t stream) {
    (void)in_sizes; (void)n_in; (void)out_size; (void)ws_size;
    const float* target = (const float*)d_in[0];
    const float* patches = (const float*)d_in[1];
    const float* points = (const float*)d_in[2];
    const float* normals = (const float*)d_in[3];
    const float* mtds = (const float*)d_in[4];
    const float* st = (const float*)d_in[5];
    const float* tmpl = (const float*)d_in[6];
    float* out = (float*)d_out;
    char* ws = (char*)d_ws;

    // ws layout (8B-aligned where needed)
    float* grid = (float*)(ws + 0);                                  // 73728 B
    float* bbF = (float*)(ws + 73728);                               // 2304 B
    float* bbE = (float*)(ws + 76032);                               // 2304 B
    unsigned long long* best_a = (unsigned long long*)(ws + 78336);  // 196608 B
    unsigned long long* best_b = (unsigned long long*)(ws + 274944); // 131072 B
    float* acc = (float*)(ws + 406016);                              // 128 B

    hipMemsetAsync(ws + 78336, 0xFF, 196608 + 131072, stream);  // best keys -> max
    hipMemsetAsync(ws + 406016, 0, 128, stream);                // accumulators -> 0

    k_coons<<<dim3(NB * NPATCH), dim3(64), 0, stream>>>(patches, grid, bbF, bbE);
    k_chamfer_a<<<dim3(8, NPATCH, NB), dim3(256), 0, stream>>>(target, points, best_a);
    k_chamfer_b<<<dim3(12, 16, NB), dim3(256), 0, stream>>>(points, target, best_b);
    k_final_a<<<dim3(NPATCH, NB), dim3(256), 0, stream>>>(points, normals, target, mtds, st,
                                                          tmpl, best_a, acc);
    k_final_b<<<dim3(16, NB), dim3(256), 0, stream>>>(target, normals, best_b, acc);
    k_collision<<<dim3(276, NB), dim3(256), 0, stream>>>(grid, bbF, bbE, acc);
    k_finish<<<1, 64, 0, stream>>>(acc, out);
}

// Round 2
// 132.707 us; speedup vs baseline: 1.3036x; 1.3036x over previous
//
#include <hip/hip_runtime.h>
#include <math.h>

#define NPATCH 24
#define NB 4
#define MPTS 256
#define MT 4096
#define NPTS (NPATCH*MPTS)   // 6144
#define GRIDPTS 64
#define SIGMA2INV 100.0f     // 1/sigma^2, sigma=0.1

// ---------- helpers ----------

__device__ inline unsigned encodeFloat(float f) {
    unsigned u = __float_as_uint(f);
    return (u & 0x80000000u) ? ~u : (u | 0x80000000u);
}
__device__ inline float decodeFloat(unsigned e) {
    return __uint_as_float((e & 0x80000000u) ? (e ^ 0x80000000u) : ~e);
}

template<int NV>
__device__ inline void blockReduceSumN(const float* vals, float* out, float* scratch) {
    int wid = threadIdx.x >> 6, lane = threadIdx.x & 63;
#pragma unroll
    for (int i = 0; i < NV; ++i) {
        float v = vals[i];
        for (int o = 32; o > 0; o >>= 1) v += __shfl_down(v, o);
        if (lane == 0) scratch[wid * NV + i] = v;
    }
    __syncthreads();
    if (threadIdx.x < NV)
        out[threadIdx.x] = scratch[0 * NV + threadIdx.x] + scratch[1 * NV + threadIdx.x] +
                           scratch[2 * NV + threadIdx.x] + scratch[3 * NV + threadIdx.x];
    __syncthreads();
}

__device__ inline float clamp01f(float x) { return fminf(fmaxf(x, 0.0f), 1.0f); }
__device__ inline float safercp(float x) {
    float s = fabsf(x) < 1e-12f ? 1e-12f : x;
    return __builtin_amdgcn_rcpf(s);
}

// point-vs-tri sq distance using precomputed tri data (4 float4 per tri):
// T[0]=(ax,ay,az, ab·a)  T[1]=(abx,aby,abz, ac·a)
// T[2]=(acx,acy,acz, ab·b) T[3]=(ac·b, ab·c, ac·c, 0)
__device__ inline float ptTriSqDistP(float px, float py, float pz, const float4* T) {
    float4 f0 = T[0], f1 = T[1], f2 = T[2], f3 = T[3];
    float ax = f0.x, ay = f0.y, az = f0.z;
    float abx = f1.x, aby = f1.y, abz = f1.z;
    float acx = f2.x, acy = f2.y, acz = f2.z;
    float abp = abx * px + aby * py + abz * pz;
    float acp = acx * px + acy * py + acz * pz;
    float d1 = abp - f0.w;
    float d2 = acp - f1.w;
    float d3 = abp - f2.w;
    float d4 = acp - f3.x;
    float d5 = abp - f3.y;
    float d6 = acp - f3.z;
    float vc = d1 * d4 - d3 * d2;
    float vb = d5 * d2 - d1 * d6;
    float va = d3 * d6 - d5 * d4;
    float t_ab = clamp01f(d1 * safercp(d1 - d3));
    float t_ac = clamp01f(d2 * safercp(d2 - d6));
    float t_bc = clamp01f((d4 - d3) * safercp((d4 - d3) + (d5 - d6)));
    float rden = safercp(va + vb + vc);
    float v = vb * rden, w = vc * rden;
    float clx = ax + abx * v + acx * w;
    float cly = ay + aby * v + acy * w;
    float clz = az + abz * v + acz * w;
    // where-chain, later overrides earlier (order matches reference)
    if (va <= 0.0f && (d4 - d3) >= 0.0f && (d5 - d6) >= 0.0f) {
        // b + (c-b)*t_bc = a+ab + (ac-ab)*t_bc
        clx = (ax + abx) + (acx - abx) * t_bc;
        cly = (ay + aby) + (acy - aby) * t_bc;
        clz = (az + abz) + (acz - abz) * t_bc;
    }
    if (vb <= 0.0f && d2 >= 0.0f && d6 <= 0.0f) {
        clx = ax + acx * t_ac; cly = ay + acy * t_ac; clz = az + acz * t_ac;
    }
    if (d6 >= 0.0f && d5 <= d6) { clx = ax + acx; cly = ay + acy; clz = az + acz; }
    if (vc <= 0.0f && d1 >= 0.0f && d3 <= 0.0f) {
        clx = ax + abx * t_ab; cly = ay + aby * t_ab; clz = az + abz * t_ab;
    }
    if (d3 >= 0.0f && d4 <= d3) { clx = ax + abx; cly = ay + aby; clz = az + abz; }
    if (d1 <= 0.0f && d2 <= 0.0f) { clx = ax; cly = ay; clz = az; }
    float dx = px - clx, dy = py - cly, dz = pz - clz;
    return dx * dx + dy * dy + dz * dz;
}

// ---------- kernel 1: Coons sampling + bboxes ----------
__global__ __launch_bounds__(64) void k_coons(const float* __restrict__ patches,
                                              float* __restrict__ grid,
                                              float* __restrict__ bbF,
                                              float* __restrict__ bbE) {
    int bp = blockIdx.x;
    int m = threadIdx.x;
    int i = m >> 3, j = m & 7;
    float s = (i == 7) ? 1.0f : (float)i * (1.0f / 7.0f);
    float t = (j == 7) ? 1.0f : (float)j * (1.0f / 7.0f);
    const float* cp = patches + bp * 36;
    float bs[4], bt[4], bs1[4], bt1[4];
    {
        float u, vv;
        u = s; vv = 1.0f - u; bs[0] = vv * vv * vv; bs[1] = 3.f * u * vv * vv; bs[2] = 3.f * u * u * vv; bs[3] = u * u * u;
        u = t; vv = 1.0f - u; bt[0] = vv * vv * vv; bt[1] = 3.f * u * vv * vv; bt[2] = 3.f * u * u * vv; bt[3] = u * u * u;
        u = 1.0f - s; vv = 1.0f - u; bs1[0] = vv * vv * vv; bs1[1] = 3.f * u * vv * vv; bs1[2] = 3.f * u * u * vv; bs1[3] = u * u * u;
        u = 1.0f - t; vv = 1.0f - u; bt1[0] = vv * vv * vv; bt1[1] = 3.f * u * vv * vv; bt1[2] = 3.f * u * u * vv; bt1[3] = u * u * u;
    }
    float g[3];
#pragma unroll
    for (int c = 0; c < 3; ++c) {
        float cb = bs[0] * cp[0 * 3 + c] + bs[1] * cp[1 * 3 + c] + bs[2] * cp[2 * 3 + c] + bs[3] * cp[3 * 3 + c];
        float cr = bt[0] * cp[3 * 3 + c] + bt[1] * cp[4 * 3 + c] + bt[2] * cp[5 * 3 + c] + bt[3] * cp[6 * 3 + c];
        float ct = bs1[0] * cp[6 * 3 + c] + bs1[1] * cp[7 * 3 + c] + bs1[2] * cp[8 * 3 + c] + bs1[3] * cp[9 * 3 + c];
        float cl = bt1[0] * cp[9 * 3 + c] + bt1[1] * cp[10 * 3 + c] + bt1[2] * cp[11 * 3 + c] + bt1[3] * cp[0 * 3 + c];
        float P00 = cp[0 * 3 + c], P10 = cp[3 * 3 + c], P11 = cp[6 * 3 + c], P01 = cp[9 * 3 + c];
        float ruled = (1.0f - t) * cb + t * ct + (1.0f - s) * cl + s * cr;
        float bil = (1.0f - s) * (1.0f - t) * P00 + s * (1.0f - t) * P10 + s * t * P11 + (1.0f - s) * t * P01;
        g[c] = ruled - bil;
        grid[(bp * GRIDPTS + m) * 3 + c] = g[c];
    }
    float mnF[3], mxF[3], mnE[3], mxE[3];
    bool edge = (m >= 56);
#pragma unroll
    for (int c = 0; c < 3; ++c) {
        mnF[c] = g[c]; mxF[c] = g[c];
        mnE[c] = edge ? g[c] : 1e30f;
        mxE[c] = edge ? g[c] : -1e30f;
    }
    for (int o = 32; o > 0; o >>= 1) {
#pragma unroll
        for (int c = 0; c < 3; ++c) {
            mnF[c] = fminf(mnF[c], __shfl_down(mnF[c], o));
            mxF[c] = fmaxf(mxF[c], __shfl_down(mxF[c], o));
            mnE[c] = fminf(mnE[c], __shfl_down(mnE[c], o));
            mxE[c] = fmaxf(mxE[c], __shfl_down(mxE[c], o));
        }
    }
    if (m == 0) {
#pragma unroll
        for (int c = 0; c < 3; ++c) {
            bbF[bp * 6 + c] = mnF[c]; bbF[bp * 6 + 3 + c] = mxF[c];
            bbE[bp * 6 + c] = mnE[c]; bbE[bp * 6 + 3 + c] = mxE[c];
        }
    }
}

// ---------- kernel 2: chamfer A ----------
__global__ __launch_bounds__(256) void k_chamfer_a(const float* __restrict__ target,
                                                   const float* __restrict__ points,
                                                   unsigned long long* __restrict__ best_a) {
    int tc = blockIdx.x;
    int p = blockIdx.y;
    int b = blockIdx.z;
    int tid = threadIdx.x;
    __shared__ float4 tg[512];
    for (int k = tid; k < 512; k += 256) {
        const float* tp = target + (size_t)(b * MT + tc * 512 + k) * 6;
        float x = tp[0], y = tp[1], z = tp[2];
        tg[k] = make_float4(x, y, z, x * x + y * y + z * z);
    }
    __syncthreads();
    const float* pp = points + (size_t)((b * NPATCH + p) * MPTS + tid) * 3;
    float px = pp[0], py = pp[1], pz = pp[2];
    float pn = px * px + py * py + pz * pz;
    float bestd = 1e30f;
    int besti = 0;
#pragma unroll 4
    for (int k = 0; k < 512; ++k) {
        float4 T = tg[k];
        float dot = px * T.x + py * T.y + pz * T.z;
        float d = (pn + T.w) - 2.0f * dot;
        if (d < bestd) { bestd = d; besti = k; }
    }
    unsigned long long key = ((unsigned long long)encodeFloat(bestd) << 32) |
                             (unsigned)(tc * 512 + besti);
    atomicMin(&best_a[(size_t)b * NPTS + p * MPTS + tid], key);
}

// ---------- kernel 3: chamfer B ----------
__global__ __launch_bounds__(256) void k_chamfer_b(const float* __restrict__ points,
                                                   const float* __restrict__ target,
                                                   unsigned long long* __restrict__ best_b) {
    int nc = blockIdx.x;
    int mc = blockIdx.y;
    int b = blockIdx.z;
    int tid = threadIdx.x;
    __shared__ float4 pt[512];
    for (int k = tid; k < 512; k += 256) {
        const float* pp = points + (size_t)(b * NPTS + nc * 512 + k) * 3;
        float x = pp[0], y = pp[1], z = pp[2];
        pt[k] = make_float4(x, y, z, x * x + y * y + z * z);
    }
    __syncthreads();
    int mt = mc * 256 + tid;
    const float* tp = target + (size_t)(b * MT + mt) * 6;
    float tx = tp[0], ty = tp[1], tz = tp[2];
    float tn2 = tx * tx + ty * ty + tz * tz;
    float bestd = 1e30f;
    int besti = 0;
#pragma unroll 4
    for (int k = 0; k < 512; ++k) {
        float4 P = pt[k];
        float dot = tx * P.x + ty * P.y + tz * P.z;
        float d = (tn2 + P.w) - 2.0f * dot;
        if (d < bestd) { bestd = d; besti = k; }
    }
    unsigned long long key = ((unsigned long long)encodeFloat(bestd) << 32) |
                             (unsigned)(nc * 512 + besti);
    atomicMin(&best_b[(size_t)b * MT + mt], key);
}

// ---------- kernel 4: finalize A + template-normals + planar ----------
__global__ __launch_bounds__(256) void k_final_a(const float* __restrict__ points,
                                                 const float* __restrict__ normals,
                                                 const float* __restrict__ target,
                                                 const float* __restrict__ mtds,
                                                 const float* __restrict__ st,
                                                 const float* __restrict__ tmpl,
                                                 const unsigned long long* __restrict__ best_a,
                                                 float* __restrict__ acc) {
    int p = blockIdx.x, b = blockIdx.y;
    int m = threadIdx.x;
    int bp = b * NPATCH + p;
    const float* pp = points + (size_t)(bp * MPTS + m) * 3;
    float px = pp[0], py = pp[1], pz = pp[2];
    const float* nr = normals + (size_t)(bp * MPTS + m) * 3;
    float nx = nr[0], ny = nr[1], nz = nr[2];
    float w = mtds[bp * MPTS + m];
    float s = st[2 * m], t = st[2 * m + 1];
    unsigned long long pk = best_a[(size_t)b * NPTS + p * MPTS + m];
    float ca = decodeFloat((unsigned)(pk >> 32));
    int ia = (int)(pk & 0xffffffffu);
    const float* tq = target + (size_t)(b * MT + ia) * 6 + 3;
    float dx = nx - tq[0], dy = ny - tq[1], dz = nz - tq[2];
    float na = dx * dx + dy * dy + dz * dz;
    const float* tm = tmpl + (size_t)(p * MPTS + m) * 3;
    float ex = tm[0] - nx, ey = tm[1] - ny, ez = tm[2] - nz;
    float tnl = ex * ex + ey * ey + ez * ez;

    float vals[18];
    vals[0] = w * ca; vals[1] = w * na; vals[2] = w; vals[3] = w * tnl;
    vals[4] = s * px; vals[5] = s * py; vals[6] = s * pz;
    vals[7] = t * px; vals[8] = t * py; vals[9] = t * pz;
    vals[10] = px; vals[11] = py; vals[12] = pz;
    vals[13] = s * s; vals[14] = s * t; vals[15] = s; vals[16] = t * t; vals[17] = t;

    __shared__ float scratch[4 * 18];
    __shared__ float red[18];
    blockReduceSumN<18>(vals, red, scratch);

    __shared__ float sol[9];
    __shared__ float smtd_sh;
    if (threadIdx.x == 0) {
        float a00 = red[13], a01 = red[14], a02 = red[15];
        float a11 = red[16], a12 = red[17], a22 = 256.0f;
        float c00 = a11 * a22 - a12 * a12;
        float c01 = a02 * a12 - a01 * a22;
        float c02 = a01 * a12 - a02 * a11;
        float det = a00 * c00 + a01 * c01 + a02 * c02;
        float id = 1.0f / det;
        float i00 = c00 * id, i01 = c01 * id, i02 = c02 * id;
        float i11 = (a00 * a22 - a02 * a02) * id;
        float i12 = (a01 * a02 - a00 * a12) * id;
        float i22 = (a00 * a11 - a01 * a01) * id;
#pragma unroll
        for (int c = 0; c < 3; ++c) {
            float b0 = red[4 + c], b1 = red[7 + c], b2 = red[10 + c];
            sol[0 * 3 + c] = i00 * b0 + i01 * b1 + i02 * b2;
            sol[1 * 3 + c] = i01 * b0 + i11 * b1 + i12 * b2;
            sol[2 * 3 + c] = i02 * b0 + i12 * b1 + i22 * b2;
        }
        smtd_sh = red[2];
        atomicAdd(&acc[0 + b], red[0]);
        atomicAdd(&acc[4 + b], red[1]);
        atomicAdd(&acc[8 + b], red[2]);
        atomicAdd(&acc[20], red[3] / red[2]);
    }
    __syncthreads();
    float rx = px - (s * sol[0] + t * sol[3] + sol[6]);
    float ry = py - (s * sol[1] + t * sol[4] + sol[7]);
    float rz = pz - (s * sol[2] + t * sol[5] + sol[8]);
    float v2 = w * (rx * rx + ry * ry + rz * rz);
    for (int o = 32; o > 0; o >>= 1) v2 += __shfl_down(v2, o);
    __shared__ float s2[4];
    if ((threadIdx.x & 63) == 0) s2[threadIdx.x >> 6] = v2;
    __syncthreads();
    if (threadIdx.x == 0)
        atomicAdd(&acc[21], (s2[0] + s2[1] + s2[2] + s2[3]) / smtd_sh);
}

// ---------- kernel 5: finalize B ----------
__global__ __launch_bounds__(256) void k_final_b(const float* __restrict__ target,
                                                 const float* __restrict__ normals,
                                                 const unsigned long long* __restrict__ best_b,
                                                 float* __restrict__ acc) {
    int mc = blockIdx.x, b = blockIdx.y;
    int mt = mc * 256 + threadIdx.x;
    unsigned long long pk = best_b[(size_t)b * MT + mt];
    float cb = decodeFloat((unsigned)(pk >> 32));
    int ib = (int)(pk & 0xffffffffu);
    const float* tq = target + (size_t)(b * MT + mt) * 6 + 3;
    const float* nr = normals + (size_t)(b * NPTS + ib) * 3;
    float dx = tq[0] - nr[0], dy = tq[1] - nr[1], dz = tq[2] - nr[2];
    float nb = dx * dx + dy * dy + dz * dz;
    float vals[2] = {cb, nb};
    __shared__ float scratch[4 * 2];
    __shared__ float red[2];
    blockReduceSumN<2>(vals, red, scratch);
    if (threadIdx.x == 0) {
        atomicAdd(&acc[12 + b], red[0]);
        atomicAdd(&acc[16 + b], red[1]);
    }
}

// ---------- kernel 6: collision (restructured: precomputed tri data, broadcast reads) ----------
__global__ __launch_bounds__(256) void k_collision(const float* __restrict__ grid,
                                                   const float* __restrict__ bbF,
                                                   const float* __restrict__ bbE,
                                                   float* __restrict__ acc) {
    int pair = blockIdx.x;
    int b = blockIdx.y;
    bool adj = pair < 24;
    int i1, i2;
    if (adj) {
        i1 = pair; i2 = (pair + 1) % NPATCH;
    } else {
        int k = pair - 24;
        i1 = 0;
        while (i1 < NPATCH) {
            int cnt = (i1 == 0) ? 21 : (22 - i1);
            if (k < cnt) break;
            k -= cnt; ++i1;
        }
        i2 = i1 + 2 + k;
    }
    bool mask = false;
    for (int bb = 0; bb < NB; ++bb) {
        const float* B1 = (adj ? bbE : bbF) + (bb * NPATCH + i1) * 6;
        const float* B2 = bbF + (bb * NPATCH + i2) * 6;
        bool it = (B1[3] >= B2[0]) && (B2[3] >= B1[0]) &&
                  (B1[4] >= B2[1]) && (B2[4] >= B1[1]) &&
                  (B1[5] >= B2[2]) && (B2[5] >= B1[2]);
        mask |= it;
    }
    if (!mask) return;

    __shared__ float P1[192], P2[192];
    __shared__ float4 TD[2][98 * 4];   // [0] = tris of patch i1, [1] = tris of patch i2
    int tid = threadIdx.x;
    for (int k = tid; k < 192; k += 256) {
        P1[k] = grid[(size_t)(b * NPATCH + i1) * 192 + k];
        P2[k] = grid[(size_t)(b * NPATCH + i2) * 192 + k];
    }
    __syncthreads();
    if (tid < 196) {
        int which = (tid >= 98) ? 1 : 0;
        int t = tid - which * 98;
        const float* P = which ? P2 : P1;
        int cell = t >> 1, ii = cell / 7, jj = cell - ii * 7;
        int v00 = ii * 8 + jj;
        int va, vb, vc;
        if (t & 1) { va = v00 + 8; vb = v00 + 9; vc = v00 + 1; }
        else       { va = v00;     vb = v00 + 8; vc = v00 + 1; }
        float ax = P[va * 3], ay = P[va * 3 + 1], az = P[va * 3 + 2];
        float bx = P[vb * 3], by = P[vb * 3 + 1], bz = P[vb * 3 + 2];
        float cx = P[vc * 3], cy = P[vc * 3 + 1], cz = P[vc * 3 + 2];
        float abx = bx - ax, aby = by - ay, abz = bz - az;
        float acx = cx - ax, acy = cy - ay, acz = cz - az;
        float ab_a = abx * ax + aby * ay + abz * az;
        float ac_a = acx * ax + acy * ay + acz * az;
        float ab_b = abx * bx + aby * by + abz * bz;
        float ac_b = acx * bx + acy * by + acz * bz;
        float ab_c = abx * cx + aby * cy + abz * cz;
        float ac_c = acx * cx + acy * cy + acz * cz;
        float4* dst = &TD[which][t * 4];
        dst[0] = make_float4(ax, ay, az, ab_a);
        dst[1] = make_float4(abx, aby, abz, ac_a);
        dst[2] = make_float4(acx, acy, acz, ab_b);
        dst[3] = make_float4(ac_b, ab_c, ac_c, 0.0f);
    }
    __syncthreads();

    float best = 1e30f;
    if (adj) {
        // 8 edge-pts of P1 vs 98 tris of P2 (784) + 64 pts of P2 vs 7 edge tris of P1 (448)
        for (int tt = tid; tt < 1232; tt += 256) {
            const float4* T;
            float px, py, pz;
            if (tt < 784) {
                int ptI = tt / 98, tri = tt - ptI * 98;
                px = P1[(56 + ptI) * 3]; py = P1[(56 + ptI) * 3 + 1]; pz = P1[(56 + ptI) * 3 + 2];
                T = &TD[1][tri * 4];
            } else {
                int r = tt - 784;
                int ptI = r / 7, e = r - ptI * 7;
                px = P2[ptI * 3]; py = P2[ptI * 3 + 1]; pz = P2[ptI * 3 + 2];
                T = &TD[0][(85 + 2 * e) * 4];   // edge tris of P1: odd tris of cells (6,j)
            }
            best = fminf(best, ptTriSqDistP(px, py, pz, T));
        }
    } else {
        // slot<64: P1 point vs P2 tris; slot>=64: P2 point vs P1 tris; half over 49 tris
        int slot = tid & 127, half = tid >> 7;
        const float* PS = (slot < 64) ? P1 : P2;
        const float4* T = (slot < 64) ? TD[1] : TD[0];
        int pi = slot & 63;
        float px = PS[pi * 3], py = PS[pi * 3 + 1], pz = PS[pi * 3 + 2];
        int t0 = half * 49;
        for (int t = t0; t < t0 + 49; ++t)
            best = fminf(best, ptTriSqDistP(px, py, pz, &T[t * 4]));
    }

    for (int o = 32; o > 0; o >>= 1) best = fminf(best, __shfl_down(best, o));
    __shared__ float sm[4];
    if ((tid & 63) == 0) sm[tid >> 6] = best;
    __syncthreads();
    if (tid == 0) {
        float d2 = fminf(fminf(sm[0], sm[1]), fminf(sm[2], sm[3]));
        atomicAdd(&acc[22], expf(-(d2 + 1e-12f) * SIGMA2INV));
    }
}

// ---------- kernel 7: combine ----------
__global__ void k_finish(const float* __restrict__ acc, float* __restrict__ out) {
    if (threadIdx.x == 0 && blockIdx.x == 0) {
        float ch = 0.0f, no = 0.0f;
        for (int b = 0; b < NB; ++b) {
            float caw = acc[0 + b] / acc[8 + b];
            float naw = acc[4 + b] / acc[8 + b];
            float cbm = acc[12 + b] / (float)MT;
            float nbm = acc[16 + b] / (float)MT;
            ch += caw + cbm;
            no += naw + nbm;
        }
        ch = ch * 0.25f * 0.5f;
        no = no * 0.25f * 0.5f;
        float tpl = acc[20] / 96.0f;
        float pl = acc[21] / 96.0f;
        float col = acc[22] * 0.25f;
        float loss = ch + no + 0.01f * col + pl + tpl;
        out[0] = loss;
        out[1] = ch;
        out[2] = no;
        out[3] = col;
        out[4] = pl;
        out[5] = tpl;
        out[6] = 0.0f;
    }
}

// ---------- launch ----------
extern "C" void kernel_launch(void* const* d_in, const int* in_sizes, int n_in,
                              void* d_out, int out_size, void* d_ws, size_t ws_size,
                              hipStream_t stream) {
    (void)in_sizes; (void)n_in; (void)out_size; (void)ws_size;
    const float* target = (const float*)d_in[0];
    const float* patches = (const float*)d_in[1];
    const float* points = (const float*)d_in[2];
    const float* normals = (const float*)d_in[3];
    const float* mtds = (const float*)d_in[4];
    const float* st = (const float*)d_in[5];
    const float* tmpl = (const float*)d_in[6];
    float* out = (float*)d_out;
    char* ws = (char*)d_ws;

    float* grid = (float*)(ws + 0);                                  // 73728 B
    float* bbF = (float*)(ws + 73728);                               // 2304 B
    float* bbE = (float*)(ws + 76032);                               // 2304 B
    unsigned long long* best_a = (unsigned long long*)(ws + 78336);  // 196608 B
    unsigned long long* best_b = (unsigned long long*)(ws + 274944); // 131072 B
    float* acc = (float*)(ws + 406016);                              // 128 B

    hipMemsetAsync(ws + 78336, 0xFF, 196608 + 131072, stream);
    hipMemsetAsync(ws + 406016, 0, 128, stream);

    k_coons<<<dim3(NB * NPATCH), dim3(64), 0, stream>>>(patches, grid, bbF, bbE);
    k_chamfer_a<<<dim3(8, NPATCH, NB), dim3(256), 0, stream>>>(target, points, best_a);
    k_chamfer_b<<<dim3(12, 16, NB), dim3(256), 0, stream>>>(points, target, best_b);
    k_final_a<<<dim3(NPATCH, NB), dim3(256), 0, stream>>>(points, normals, target, mtds, st,
                                                          tmpl, best_a, acc);
    k_final_b<<<dim3(16, NB), dim3(256), 0, stream>>>(target, normals, best_b, acc);
    k_collision<<<dim3(276, NB), dim3(256), 0, stream>>>(grid, bbF, bbE, acc);
    k_finish<<<1, 64, 0, stream>>>(acc, out);
}

// Round 3
// 122.413 us; speedup vs baseline: 1.4132x; 1.0841x over previous
//
#include <hip/hip_runtime.h>
#include <math.h>

#define NPATCH 24
#define NB 4
#define MPTS 256
#define MT 4096
#define NPTS (NPATCH*MPTS)   // 6144
#define GRIDPTS 64
#define SIGMA2INV 100.0f
#define PRUNE_MARGIN 0.45f   // exp(-100*0.45^2) ~ 2e-9, negligible vs 5.16 threshold

// ---------- helpers ----------

__device__ inline unsigned encodeFloat(float f) {
    unsigned u = __float_as_uint(f);
    return (u & 0x80000000u) ? ~u : (u | 0x80000000u);
}
__device__ inline float decodeFloat(unsigned e) {
    return __uint_as_float((e & 0x80000000u) ? (e ^ 0x80000000u) : ~e);
}

template<int NV>
__device__ inline void blockReduceSumN(const float* vals, float* out, float* scratch) {
    int wid = threadIdx.x >> 6, lane = threadIdx.x & 63;
#pragma unroll
    for (int i = 0; i < NV; ++i) {
        float v = vals[i];
        for (int o = 32; o > 0; o >>= 1) v += __shfl_down(v, o);
        if (lane == 0) scratch[wid * NV + i] = v;
    }
    __syncthreads();
    if (threadIdx.x < NV)
        out[threadIdx.x] = scratch[0 * NV + threadIdx.x] + scratch[1 * NV + threadIdx.x] +
                           scratch[2 * NV + threadIdx.x] + scratch[3 * NV + threadIdx.x];
    __syncthreads();
}

__device__ inline float clamp01f(float x) { return fminf(fmaxf(x, 0.0f), 1.0f); }
__device__ inline float safercp(float x) {
    float s = fabsf(x) < 1e-12f ? 1e-12f : x;
    return __builtin_amdgcn_rcpf(s);
}

// point-vs-tri sq distance using precomputed tri data (4 float4 per tri):
// T[0]=(ax,ay,az, ab.a)  T[1]=(abx,aby,abz, ac.a)
// T[2]=(acx,acy,acz, ab.b) T[3]=(ac.b, ab.c, ac.c, 0)
__device__ inline float ptTriSqDistP(float px, float py, float pz, const float4* T) {
    float4 f0 = T[0], f1 = T[1], f2 = T[2], f3 = T[3];
    float ax = f0.x, ay = f0.y, az = f0.z;
    float abx = f1.x, aby = f1.y, abz = f1.z;
    float acx = f2.x, acy = f2.y, acz = f2.z;
    float abp = abx * px + aby * py + abz * pz;
    float acp = acx * px + acy * py + acz * pz;
    float d1 = abp - f0.w;
    float d2 = acp - f1.w;
    float d3 = abp - f2.w;
    float d4 = acp - f3.x;
    float d5 = abp - f3.y;
    float d6 = acp - f3.z;
    float vc = d1 * d4 - d3 * d2;
    float vb = d5 * d2 - d1 * d6;
    float va = d3 * d6 - d5 * d4;
    float t_ab = clamp01f(d1 * safercp(d1 - d3));
    float t_ac = clamp01f(d2 * safercp(d2 - d6));
    float t_bc = clamp01f((d4 - d3) * safercp((d4 - d3) + (d5 - d6)));
    float rden = safercp(va + vb + vc);
    float v = vb * rden, w = vc * rden;
    float clx = ax + abx * v + acx * w;
    float cly = ay + aby * v + acy * w;
    float clz = az + abz * v + acz * w;
    if (va <= 0.0f && (d4 - d3) >= 0.0f && (d5 - d6) >= 0.0f) {
        clx = (ax + abx) + (acx - abx) * t_bc;
        cly = (ay + aby) + (acy - aby) * t_bc;
        clz = (az + abz) + (acz - abz) * t_bc;
    }
    if (vb <= 0.0f && d2 >= 0.0f && d6 <= 0.0f) {
        clx = ax + acx * t_ac; cly = ay + acy * t_ac; clz = az + acz * t_ac;
    }
    if (d6 >= 0.0f && d5 <= d6) { clx = ax + acx; cly = ay + acy; clz = az + acz; }
    if (vc <= 0.0f && d1 >= 0.0f && d3 <= 0.0f) {
        clx = ax + abx * t_ab; cly = ay + aby * t_ab; clz = az + abz * t_ab;
    }
    if (d3 >= 0.0f && d4 <= d3) { clx = ax + abx; cly = ay + aby; clz = az + abz; }
    if (d1 <= 0.0f && d2 <= 0.0f) { clx = ax; cly = ay; clz = az; }
    float dx = px - clx, dy = py - cly, dz = pz - clz;
    return dx * dx + dy * dy + dz * dz;
}

// ---------- kernel 1: Coons sampling + bboxes ----------
__global__ __launch_bounds__(64) void k_coons(const float* __restrict__ patches,
                                              float* __restrict__ grid,
                                              float* __restrict__ bbF,
                                              float* __restrict__ bbE) {
    int bp = blockIdx.x;
    int m = threadIdx.x;
    int i = m >> 3, j = m & 7;
    float s = (i == 7) ? 1.0f : (float)i * (1.0f / 7.0f);
    float t = (j == 7) ? 1.0f : (float)j * (1.0f / 7.0f);
    const float* cp = patches + bp * 36;
    float bs[4], bt[4], bs1[4], bt1[4];
    {
        float u, vv;
        u = s; vv = 1.0f - u; bs[0] = vv * vv * vv; bs[1] = 3.f * u * vv * vv; bs[2] = 3.f * u * u * vv; bs[3] = u * u * u;
        u = t; vv = 1.0f - u; bt[0] = vv * vv * vv; bt[1] = 3.f * u * vv * vv; bt[2] = 3.f * u * u * vv; bt[3] = u * u * u;
        u = 1.0f - s; vv = 1.0f - u; bs1[0] = vv * vv * vv; bs1[1] = 3.f * u * vv * vv; bs1[2] = 3.f * u * u * vv; bs1[3] = u * u * u;
        u = 1.0f - t; vv = 1.0f - u; bt1[0] = vv * vv * vv; bt1[1] = 3.f * u * vv * vv; bt1[2] = 3.f * u * u * vv; bt1[3] = u * u * u;
    }
    float g[3];
#pragma unroll
    for (int c = 0; c < 3; ++c) {
        float cb = bs[0] * cp[0 * 3 + c] + bs[1] * cp[1 * 3 + c] + bs[2] * cp[2 * 3 + c] + bs[3] * cp[3 * 3 + c];
        float cr = bt[0] * cp[3 * 3 + c] + bt[1] * cp[4 * 3 + c] + bt[2] * cp[5 * 3 + c] + bt[3] * cp[6 * 3 + c];
        float ct = bs1[0] * cp[6 * 3 + c] + bs1[1] * cp[7 * 3 + c] + bs1[2] * cp[8 * 3 + c] + bs1[3] * cp[9 * 3 + c];
        float cl = bt1[0] * cp[9 * 3 + c] + bt1[1] * cp[10 * 3 + c] + bt1[2] * cp[11 * 3 + c] + bt1[3] * cp[0 * 3 + c];
        float P00 = cp[0 * 3 + c], P10 = cp[3 * 3 + c], P11 = cp[6 * 3 + c], P01 = cp[9 * 3 + c];
        float ruled = (1.0f - t) * cb + t * ct + (1.0f - s) * cl + s * cr;
        float bil = (1.0f - s) * (1.0f - t) * P00 + s * (1.0f - t) * P10 + s * t * P11 + (1.0f - s) * t * P01;
        g[c] = ruled - bil;
        grid[(bp * GRIDPTS + m) * 3 + c] = g[c];
    }
    float mnF[3], mxF[3], mnE[3], mxE[3];
    bool edge = (m >= 56);
#pragma unroll
    for (int c = 0; c < 3; ++c) {
        mnF[c] = g[c]; mxF[c] = g[c];
        mnE[c] = edge ? g[c] : 1e30f;
        mxE[c] = edge ? g[c] : -1e30f;
    }
    for (int o = 32; o > 0; o >>= 1) {
#pragma unroll
        for (int c = 0; c < 3; ++c) {
            mnF[c] = fminf(mnF[c], __shfl_down(mnF[c], o));
            mxF[c] = fmaxf(mxF[c], __shfl_down(mxF[c], o));
            mnE[c] = fminf(mnE[c], __shfl_down(mnE[c], o));
            mxE[c] = fmaxf(mxE[c], __shfl_down(mxE[c], o));
        }
    }
    if (m == 0) {
#pragma unroll
        for (int c = 0; c < 3; ++c) {
            bbF[bp * 6 + c] = mnF[c]; bbF[bp * 6 + 3 + c] = mxF[c];
            bbE[bp * 6 + c] = mnE[c]; bbE[bp * 6 + 3 + c] = mxE[c];
        }
    }
}

// ---------- kernel 1b: per-patch triangle data + prune spheres ----------
__global__ __launch_bounds__(128) void k_tridata(const float* __restrict__ grid,
                                                 float4* __restrict__ TDg,
                                                 float4* __restrict__ TSg) {
    int bp = blockIdx.x;          // b*24+p
    int t = threadIdx.x;
    if (t >= 98) return;
    const float* P = grid + (size_t)bp * 192;
    int cell = t >> 1, ii = cell / 7, jj = cell - ii * 7;
    int v00 = ii * 8 + jj;
    int va, vb, vc;
    if (t & 1) { va = v00 + 8; vb = v00 + 9; vc = v00 + 1; }
    else       { va = v00;     vb = v00 + 8; vc = v00 + 1; }
    float ax = P[va * 3], ay = P[va * 3 + 1], az = P[va * 3 + 2];
    float bx = P[vb * 3], by = P[vb * 3 + 1], bz = P[vb * 3 + 2];
    float cx = P[vc * 3], cy = P[vc * 3 + 1], cz = P[vc * 3 + 2];
    float abx = bx - ax, aby = by - ay, abz = bz - az;
    float acx = cx - ax, acy = cy - ay, acz = cz - az;
    float ab_a = abx * ax + aby * ay + abz * az;
    float ac_a = acx * ax + acy * ay + acz * az;
    float ab_b = abx * bx + aby * by + abz * bz;
    float ac_b = acx * bx + acy * by + acz * bz;
    float ab_c = abx * cx + aby * cy + abz * cz;
    float ac_c = acx * cx + acy * cy + acz * cz;
    float4* dst = TDg + ((size_t)bp * 98 + t) * 4;
    dst[0] = make_float4(ax, ay, az, ab_a);
    dst[1] = make_float4(abx, aby, abz, ac_a);
    dst[2] = make_float4(acx, acy, acz, ab_b);
    dst[3] = make_float4(ac_b, ab_c, ac_c, 0.0f);
    // prune sphere: centroid + (r + margin)^2
    float gx = (ax + bx + cx) * (1.0f / 3.0f);
    float gy = (ay + by + cy) * (1.0f / 3.0f);
    float gz = (az + bz + cz) * (1.0f / 3.0f);
    float ra = (ax - gx) * (ax - gx) + (ay - gy) * (ay - gy) + (az - gz) * (az - gz);
    float rb = (bx - gx) * (bx - gx) + (by - gy) * (by - gy) + (bz - gz) * (bz - gz);
    float rc = (cx - gx) * (cx - gx) + (cy - gy) * (cy - gy) + (cz - gz) * (cz - gz);
    float r = sqrtf(fmaxf(ra, fmaxf(rb, rc))) + PRUNE_MARGIN;
    TSg[(size_t)bp * 98 + t] = make_float4(gx, gy, gz, r * r);
}

// ---------- mega kernel: chamfer A + chamfer B + collision ----------
// blockIdx.x in [0,912): [0,192) chamferA, [192,384) chamferB,
//                        [384,408) collision-adjacent, [408,912) collision-nonadj (x2 dirs)
__global__ __launch_bounds__(256) void k_mega(const float* __restrict__ target,
                                              const float* __restrict__ points,
                                              const float* __restrict__ grid,
                                              const float4* __restrict__ TDg,
                                              const float4* __restrict__ TSg,
                                              const float* __restrict__ bbF,
                                              const float* __restrict__ bbE,
                                              unsigned long long* __restrict__ best_a,
                                              unsigned long long* __restrict__ best_b,
                                              unsigned* __restrict__ pairmin) {
    __shared__ float4 smem[512];
    __shared__ float sred[4];
    int id = blockIdx.x;
    int b = blockIdx.y;
    int tid = threadIdx.x;

    if (id < 192) {
        // ---- chamfer A: points (b,p,tid) vs targets chunk tc ----
        int tc = id & 7, p = id >> 3;
        for (int k = tid; k < 512; k += 256) {
            const float* tp = target + (size_t)(b * MT + tc * 512 + k) * 6;
            float x = tp[0], y = tp[1], z = tp[2];
            smem[k] = make_float4(x, y, z, x * x + y * y + z * z);
        }
        __syncthreads();
        const float* pp = points + (size_t)((b * NPATCH + p) * MPTS + tid) * 3;
        float px = pp[0], py = pp[1], pz = pp[2];
        float pn = px * px + py * py + pz * pz;
        float bestd = 1e30f;
        int besti = 0;
#pragma unroll 4
        for (int k = 0; k < 512; ++k) {
            float4 T = smem[k];
            float dot = px * T.x + py * T.y + pz * T.z;
            float d = (pn + T.w) - 2.0f * dot;
            if (d < bestd) { bestd = d; besti = k; }
        }
        unsigned long long key = ((unsigned long long)encodeFloat(bestd) << 32) |
                                 (unsigned)(tc * 512 + besti);
        atomicMin(&best_a[(size_t)b * NPTS + p * MPTS + tid], key);
        return;
    }
    if (id < 384) {
        // ---- chamfer B: targets (b, mc*256+tid) vs points chunk nc ----
        int r = id - 192;
        int nc = r % 12, mc = r / 12;
        for (int k = tid; k < 512; k += 256) {
            const float* pp = points + (size_t)(b * NPTS + nc * 512 + k) * 3;
            float x = pp[0], y = pp[1], z = pp[2];
            smem[k] = make_float4(x, y, z, x * x + y * y + z * z);
        }
        __syncthreads();
        int mt = mc * 256 + tid;
        const float* tp = target + (size_t)(b * MT + mt) * 6;
        float tx = tp[0], ty = tp[1], tz = tp[2];
        float tn2 = tx * tx + ty * ty + tz * tz;
        float bestd = 1e30f;
        int besti = 0;
#pragma unroll 4
        for (int k = 0; k < 512; ++k) {
            float4 P = smem[k];
            float dot = tx * P.x + ty * P.y + tz * P.z;
            float d = (tn2 + P.w) - 2.0f * dot;
            if (d < bestd) { bestd = d; besti = k; }
        }
        unsigned long long key = ((unsigned long long)encodeFloat(bestd) << 32) |
                                 (unsigned)(nc * 512 + besti);
        atomicMin(&best_b[(size_t)b * MT + mt], key);
        return;
    }

    float best = 1e30f;
    int pairIdx;   // index into pairmin[b*276 + pairIdx]

    if (id < 408) {
        // ---- collision, adjacent pair ----
        int pair = id - 384;
        pairIdx = pair;
        int i1 = pair, i2 = (pair + 1) % NPATCH;
        bool mask = false;
        for (int bb = 0; bb < NB; ++bb) {
            const float* B1 = bbE + (bb * NPATCH + i1) * 6;
            const float* B2 = bbF + (bb * NPATCH + i2) * 6;
            bool it = (B1[3] >= B2[0]) && (B2[3] >= B1[0]) &&
                      (B1[4] >= B2[1]) && (B2[4] >= B1[1]) &&
                      (B1[5] >= B2[2]) && (B2[5] >= B1[2]);
            mask |= it;
        }
        if (!mask) return;
        const float* P1 = grid + (size_t)(b * NPATCH + i1) * 192;
        const float* P2 = grid + (size_t)(b * NPATCH + i2) * 192;
        const float4* T1 = TDg + (size_t)(b * NPATCH + i1) * 98 * 4;
        const float4* T2 = TDg + (size_t)(b * NPATCH + i2) * 98 * 4;
        for (int tt = tid; tt < 1232; tt += 256) {
            const float4* T;
            float px, py, pz;
            if (tt < 784) {
                int ptI = tt / 98, tri = tt - ptI * 98;
                const float* gp = P1 + (56 + ptI) * 3;
                px = gp[0]; py = gp[1]; pz = gp[2];
                T = T2 + tri * 4;
            } else {
                int rr = tt - 784;
                int ptI = rr / 7, e = rr - ptI * 7;
                const float* gp = P2 + ptI * 3;
                px = gp[0]; py = gp[1]; pz = gp[2];
                T = T1 + (85 + 2 * e) * 4;
            }
            best = fminf(best, ptTriSqDistP(px, py, pz, T));
        }
    } else {
        // ---- collision, non-adjacent pair, one direction per block ----
        int r = id - 408;
        int pi2 = r >> 1, dir = r & 1;
        pairIdx = 24 + pi2;
        int k = pi2, i1 = 0;
        while (i1 < NPATCH) {
            int cnt = (i1 == 0) ? 21 : (22 - i1);
            if (k < cnt) break;
            k -= cnt; ++i1;
        }
        int i2 = i1 + 2 + k;
        bool mask = false;
        for (int bb = 0; bb < NB; ++bb) {
            const float* B1 = bbF + (bb * NPATCH + i1) * 6;
            const float* B2 = bbF + (bb * NPATCH + i2) * 6;
            bool it = (B1[3] >= B2[0]) && (B2[3] >= B1[0]) &&
                      (B1[4] >= B2[1]) && (B2[4] >= B1[1]) &&
                      (B1[5] >= B2[2]) && (B2[5] >= B1[2]);
            mask |= it;
        }
        if (!mask) return;
        int ip_pts = dir ? i2 : i1;
        int ip_tri = dir ? i1 : i2;
        int lane_pt = tid & 63;
        const float* gp = grid + ((size_t)(b * NPATCH + ip_pts) * 64 + lane_pt) * 3;
        float px = gp[0], py = gp[1], pz = gp[2];
        const float4* TD = TDg + (size_t)(b * NPATCH + ip_tri) * 98 * 4;
        const float4* TS = TSg + (size_t)(b * NPATCH + ip_tri) * 98;
        int wq = __builtin_amdgcn_readfirstlane(tid >> 6);   // wave-uniform quarter
        for (int t = wq; t < 98; t += 4) {
            float4 S = TS[t];
            float ddx = px - S.x, ddy = py - S.y, ddz = pz - S.z;
            float lb = ddx * ddx + ddy * ddy + ddz * ddz;
            if (__all(lb > S.w)) continue;   // whole wave beyond prune sphere
            best = fminf(best, ptTriSqDistP(px, py, pz, TD + t * 4));
        }
    }

    // block-reduce min, then atomicMin into pairmin
    for (int o = 32; o > 0; o >>= 1) best = fminf(best, __shfl_down(best, o));
    if ((tid & 63) == 0) sred[tid >> 6] = best;
    __syncthreads();
    if (tid == 0) {
        float d2 = fminf(fminf(sred[0], sred[1]), fminf(sred[2], sred[3]));
        atomicMin(&pairmin[b * 276 + pairIdx], encodeFloat(d2));
    }
}

// ---------- finalize A (per (b,p)) + finalize B fused ----------
__global__ __launch_bounds__(256) void k_final(const float* __restrict__ points,
                                               const float* __restrict__ normals,
                                               const float* __restrict__ target,
                                               const float* __restrict__ mtds,
                                               const float* __restrict__ st,
                                               const float* __restrict__ tmpl,
                                               const unsigned long long* __restrict__ best_a,
                                               const unsigned long long* __restrict__ best_b,
                                               float* __restrict__ acc) {
    int id = blockIdx.x, b = blockIdx.y;
    if (id < 24) {
        int p = id;
        int m = threadIdx.x;
        int bp = b * NPATCH + p;
        const float* pp = points + (size_t)(bp * MPTS + m) * 3;
        float px = pp[0], py = pp[1], pz = pp[2];
        const float* nr = normals + (size_t)(bp * MPTS + m) * 3;
        float nx = nr[0], ny = nr[1], nz = nr[2];
        float w = mtds[bp * MPTS + m];
        float s = st[2 * m], t = st[2 * m + 1];
        unsigned long long pk = best_a[(size_t)b * NPTS + p * MPTS + m];
        float ca = decodeFloat((unsigned)(pk >> 32));
        int ia = (int)(pk & 0xffffffffu);
        const float* tq = target + (size_t)(b * MT + ia) * 6 + 3;
        float dx = nx - tq[0], dy = ny - tq[1], dz = nz - tq[2];
        float na = dx * dx + dy * dy + dz * dz;
        const float* tm = tmpl + (size_t)(p * MPTS + m) * 3;
        float ex = tm[0] - nx, ey = tm[1] - ny, ez = tm[2] - nz;
        float tnl = ex * ex + ey * ey + ez * ez;

        float vals[18];
        vals[0] = w * ca; vals[1] = w * na; vals[2] = w; vals[3] = w * tnl;
        vals[4] = s * px; vals[5] = s * py; vals[6] = s * pz;
        vals[7] = t * px; vals[8] = t * py; vals[9] = t * pz;
        vals[10] = px; vals[11] = py; vals[12] = pz;
        vals[13] = s * s; vals[14] = s * t; vals[15] = s; vals[16] = t * t; vals[17] = t;

        __shared__ float scratch[4 * 18];
        __shared__ float red[18];
        blockReduceSumN<18>(vals, red, scratch);

        __shared__ float sol[9];
        __shared__ float smtd_sh;
        if (threadIdx.x == 0) {
            float a00 = red[13], a01 = red[14], a02 = red[15];
            float a11 = red[16], a12 = red[17], a22 = 256.0f;
            float c00 = a11 * a22 - a12 * a12;
            float c01 = a02 * a12 - a01 * a22;
            float c02 = a01 * a12 - a02 * a11;
            float det = a00 * c00 + a01 * c01 + a02 * c02;
            float idet = 1.0f / det;
            float i00 = c00 * idet, i01 = c01 * idet, i02 = c02 * idet;
            float i11 = (a00 * a22 - a02 * a02) * idet;
            float i12 = (a01 * a02 - a00 * a12) * idet;
            float i22 = (a00 * a11 - a01 * a01) * idet;
#pragma unroll
            for (int c = 0; c < 3; ++c) {
                float b0 = red[4 + c], b1 = red[7 + c], b2 = red[10 + c];
                sol[0 * 3 + c] = i00 * b0 + i01 * b1 + i02 * b2;
                sol[1 * 3 + c] = i01 * b0 + i11 * b1 + i12 * b2;
                sol[2 * 3 + c] = i02 * b0 + i12 * b1 + i22 * b2;
            }
            smtd_sh = red[2];
            atomicAdd(&acc[0 + b], red[0]);
            atomicAdd(&acc[4 + b], red[1]);
            atomicAdd(&acc[8 + b], red[2]);
            atomicAdd(&acc[20], red[3] / red[2]);
        }
        __syncthreads();
        float rx = px - (s * sol[0] + t * sol[3] + sol[6]);
        float ry = py - (s * sol[1] + t * sol[4] + sol[7]);
        float rz = pz - (s * sol[2] + t * sol[5] + sol[8]);
        float v2 = w * (rx * rx + ry * ry + rz * rz);
        for (int o = 32; o > 0; o >>= 1) v2 += __shfl_down(v2, o);
        __shared__ float s2[4];
        if ((threadIdx.x & 63) == 0) s2[threadIdx.x >> 6] = v2;
        __syncthreads();
        if (threadIdx.x == 0)
            atomicAdd(&acc[21], (s2[0] + s2[1] + s2[2] + s2[3]) / smtd_sh);
    } else {
        int mc = id - 24;
        int mt = mc * 256 + threadIdx.x;
        unsigned long long pk = best_b[(size_t)b * MT + mt];
        float cb = decodeFloat((unsigned)(pk >> 32));
        int ib = (int)(pk & 0xffffffffu);
        const float* tq = target + (size_t)(b * MT + mt) * 6 + 3;
        const float* nr = normals + (size_t)(b * NPTS + ib) * 3;
        float dx = tq[0] - nr[0], dy = tq[1] - nr[1], dz = tq[2] - nr[2];
        float nb = dx * dx + dy * dy + dz * dz;
        float vals[2] = {cb, nb};
        __shared__ float scratchB[4 * 2];
        __shared__ float redB[2];
        blockReduceSumN<2>(vals, redB, scratchB);
        if (threadIdx.x == 0) {
            atomicAdd(&acc[12 + b], redB[0]);
            atomicAdd(&acc[16 + b], redB[1]);
        }
    }
}

// ---------- finish: collision exp-sum + combine ----------
__global__ __launch_bounds__(256) void k_finish(const float* __restrict__ acc,
                                                const unsigned* __restrict__ pairmin,
                                                float* __restrict__ out) {
    int tid = threadIdx.x;
    float s = 0.0f;
    for (int idx = tid; idx < 4 * 276; idx += 256) {
        unsigned key = pairmin[idx];
        if (key != 0xFFFFFFFFu) {
            float d2 = decodeFloat(key);
            s += expf(-(d2 + 1e-12f) * SIGMA2INV);
        }
    }
    for (int o = 32; o > 0; o >>= 1) s += __shfl_down(s, o);
    __shared__ float sred[4];
    if ((tid & 63) == 0) sred[tid >> 6] = s;
    __syncthreads();
    if (tid == 0) {
        float col = (sred[0] + sred[1] + sred[2] + sred[3]) * 0.25f;
        float ch = 0.0f, no = 0.0f;
        for (int b = 0; b < NB; ++b) {
            float caw = acc[0 + b] / acc[8 + b];
            float naw = acc[4 + b] / acc[8 + b];
            float cbm = acc[12 + b] / (float)MT;
            float nbm = acc[16 + b] / (float)MT;
            ch += caw + cbm;
            no += naw + nbm;
        }
        ch = ch * 0.25f * 0.5f;
        no = no * 0.25f * 0.5f;
        float tpl = acc[20] / 96.0f;
        float pl = acc[21] / 96.0f;
        float loss = ch + no + 0.01f * col + pl + tpl;
        out[0] = loss;
        out[1] = ch;
        out[2] = no;
        out[3] = col;
        out[4] = pl;
        out[5] = tpl;
        out[6] = 0.0f;
    }
}

// ---------- launch ----------
extern "C" void kernel_launch(void* const* d_in, const int* in_sizes, int n_in,
                              void* d_out, int out_size, void* d_ws, size_t ws_size,
                              hipStream_t stream) {
    (void)in_sizes; (void)n_in; (void)out_size; (void)ws_size;
    const float* target = (const float*)d_in[0];
    const float* patches = (const float*)d_in[1];
    const float* points = (const float*)d_in[2];
    const float* normals = (const float*)d_in[3];
    const float* mtds = (const float*)d_in[4];
    const float* st = (const float*)d_in[5];
    const float* tmpl = (const float*)d_in[6];
    float* out = (float*)d_out;
    char* ws = (char*)d_ws;

    // ws layout
    float* grid = (float*)(ws + 0);                                  //  73728
    float* bbF = (float*)(ws + 73728);                               //   2304
    float* bbE = (float*)(ws + 76032);                               //   2304
    unsigned long long* best_a = (unsigned long long*)(ws + 78336);  // 196608
    unsigned long long* best_b = (unsigned long long*)(ws + 274944); // 131072
    unsigned* pairmin = (unsigned*)(ws + 406016);                    //   4416
    float* acc = (float*)(ws + 410432);                              //    128
    float4* TDg = (float4*)(ws + 410560);                            // 602112
    float4* TSg = (float4*)(ws + 1012672);                           // 150528  (ends 1163200)

    hipMemsetAsync(ws + 78336, 0xFF, 196608 + 131072 + 4416, stream);  // best keys + pairmin
    hipMemsetAsync(ws + 410432, 0, 128, stream);                       // accumulators

    k_coons<<<dim3(NB * NPATCH), dim3(64), 0, stream>>>(patches, grid, bbF, bbE);
    k_tridata<<<dim3(NB * NPATCH), dim3(128), 0, stream>>>(grid, TDg, TSg);
    k_mega<<<dim3(912, NB), dim3(256), 0, stream>>>(target, points, grid, TDg, TSg,
                                                    bbF, bbE, best_a, best_b, pairmin);
    k_final<<<dim3(40, NB), dim3(256), 0, stream>>>(points, normals, target, mtds, st,
                                                    tmpl, best_a, best_b, acc);
    k_finish<<<1, 256, 0, stream>>>(acc, pairmin, out);
}